// Round 4
// baseline (419.464 us; speedup 1.0000x reference)
//
#include <hip/hip_runtime.h>
#include <stdint.h>

using f32x4  = __attribute__((ext_vector_type(4))) float;
using short8 = __attribute__((ext_vector_type(8))) short;
typedef unsigned short u16;
typedef unsigned int   u32;

// B=8, H=8, L=1024, DM=512, DK=DV=64.  M = B*L = 8192.

static __device__ __forceinline__ u16 f2bf(float f) {
  union { float f; u32 u; } v; v.f = f;
  u32 r = v.u + 0x7fffu + ((v.u >> 16) & 1u);   // RNE
  return (u16)(r >> 16);
}
static __device__ __forceinline__ float bf2f(u16 u) {
  union { u32 u; float f; } v; v.u = ((u32)u) << 16;
  return v.f;
}

// ------- 4 weight transposes in one launch: W [512k][512n] -> Wt [n][k] bf16
__global__ __launch_bounds__(256) void k_wt4(const float* __restrict__ W0, const float* __restrict__ W1,
                                             const float* __restrict__ W2, const float* __restrict__ W3,
                                             u16* __restrict__ T0, u16* __restrict__ T1,
                                             u16* __restrict__ T2, u16* __restrict__ T3) {
  const float* W = (blockIdx.z == 0) ? W0 : (blockIdx.z == 1) ? W1 : (blockIdx.z == 2) ? W2 : W3;
  u16* T = (blockIdx.z == 0) ? T0 : (blockIdx.z == 1) ? T1 : (blockIdx.z == 2) ? T2 : T3;
  __shared__ float t[32][33];
  int tx = threadIdx.x & 31, ty = threadIdx.x >> 5;   // 32 x 8
  int x0 = blockIdx.x * 32, y0 = blockIdx.y * 32;     // x = n, y = k
  #pragma unroll
  for (int i = 0; i < 4; i++)
    t[ty + i*8][tx] = W[(y0 + ty + i*8) * 512 + (x0 + tx)];
  __syncthreads();
  #pragma unroll
  for (int i = 0; i < 4; i++)
    T[(x0 + ty + i*8) * 512 + (y0 + tx)] = f2bf(t[tx][ty + i*8]);
}

// ------------- rel embeddings: relk80 [80][64] (zero-pad rows>=65),
//               relvT [64 dv][96 bucket] (zero-pad buckets>=65) -------------
__global__ __launch_bounds__(256) void k_prep_rel(const float* __restrict__ rk,
                                                  const float* __restrict__ rv,
                                                  u16* __restrict__ relk80,
                                                  u16* __restrict__ relvT) {
  int i = blockIdx.x * 256 + threadIdx.x;
  if (i < 80*64) {
    int row = i >> 6;
    relk80[i] = (row < 65) ? f2bf(rk[i]) : (u16)0;
  }
  int j = i - 80*64;
  if (j >= 0 && j < 64*96) {
    int dv = j / 96, bk = j % 96;
    relvT[j] = (bk < 65) ? f2bf(rv[bk*64 + dv]) : (u16)0;
  }
}

// ------------- pack rel_matrix | mask<<7 | bf16(rel_mask)<<16 -> u32 -------
__global__ __launch_bounds__(256) void k_pack(const int* __restrict__ rm,
                                              const float* __restrict__ rw,
                                              const unsigned char* __restrict__ mk,
                                              u32* __restrict__ outp) {
  int i = blockIdx.x * 256 + threadIdx.x;     // x4 elements
  int4   r4 = ((const int4*)rm)[i];
  float4 w4 = ((const float4*)rw)[i];
  uchar4 m4 = ((const uchar4*)mk)[i];
  uint4 o;
  o.x = (u32)(r4.x & 63) | (m4.x ? 128u : 0u) | ((u32)f2bf(w4.x) << 16);
  o.y = (u32)(r4.y & 63) | (m4.y ? 128u : 0u) | ((u32)f2bf(w4.y) << 16);
  o.z = (u32)(r4.z & 63) | (m4.z ? 128u : 0u) | ((u32)f2bf(w4.z) << 16);
  o.w = (u32)(r4.w & 63) | (m4.w ? 128u : 0u) | ((u32)f2bf(w4.w) << 16);
  ((uint4*)outp)[i] = o;
}

// ---------------- bf16 MFMA GEMM: C[8192,512] = X_f32[8192,512] @ Wt^T + bias
// 128x128 tiles, grid (4,64).  fp32 X converted to bf16 during staging.
__global__ __launch_bounds__(256) void k_gemm(const float* __restrict__ X,
                                              const u16* __restrict__ Wt,
                                              const float* __restrict__ bias,
                                              void* __restrict__ outp,
                                              int mode, float scale) {
  __shared__ u16 As[128*32];   // [m][k]
  __shared__ u16 Bs[128*32];   // [n][k]
  int tid = threadIdx.x;
  int lane = tid & 63, wv = tid >> 6;
  int quad = lane >> 4, l15 = lane & 15;
  int n0 = blockIdx.x * 128, m0 = blockIdx.y * 128;
  int wm = (wv >> 1) * 64, wn = (wv & 1) * 64;
  f32x4 acc[4][4];
  #pragma unroll
  for (int i = 0; i < 4; i++)
    #pragma unroll
    for (int j = 0; j < 4; j++)
      acc[i][j] = (f32x4){0.f, 0.f, 0.f, 0.f};

  float4 areg[4]; short8 breg[2];
  #pragma unroll
  for (int j = 0; j < 4; j++) {
    int f = tid + 256*j; int r = f >> 3, p = f & 7;
    areg[j] = ((const float4*)(X + (m0 + r)*512 + p*4))[0];
  }
  #pragma unroll
  for (int j = 0; j < 2; j++) {
    int f = tid + 256*j; int r = f >> 2, p = f & 3;
    breg[j] = *(const short8*)(Wt + (n0 + r)*512 + p*8);
  }

  for (int k0 = 0; k0 < 512; k0 += 32) {
    __syncthreads();
    #pragma unroll
    for (int j = 0; j < 4; j++) {
      int f = tid + 256*j; int r = f >> 3, p = f & 7;
      ushort4 o;
      o.x = f2bf(areg[j].x); o.y = f2bf(areg[j].y);
      o.z = f2bf(areg[j].z); o.w = f2bf(areg[j].w);
      *(ushort4*)&As[r*32 + p*4] = o;
    }
    #pragma unroll
    for (int j = 0; j < 2; j++) {
      int f = tid + 256*j; int r = f >> 2, p = f & 3;
      *(short8*)&Bs[r*32 + p*8] = breg[j];
    }
    __syncthreads();
    int kn = (k0 + 32 < 512) ? (k0 + 32) : 0;
    #pragma unroll
    for (int j = 0; j < 4; j++) {
      int f = tid + 256*j; int r = f >> 3, p = f & 7;
      areg[j] = ((const float4*)(X + (m0 + r)*512 + kn + p*4))[0];
    }
    #pragma unroll
    for (int j = 0; j < 2; j++) {
      int f = tid + 256*j; int r = f >> 2, p = f & 3;
      breg[j] = *(const short8*)(Wt + (n0 + r)*512 + kn + p*8);
    }

    short8 af[4], bfr[4];
    #pragma unroll
    for (int i = 0; i < 4; i++) af[i] = *(const short8*)&As[(wm + i*16 + l15)*32 + quad*8];
    #pragma unroll
    for (int j = 0; j < 4; j++) bfr[j] = *(const short8*)&Bs[(wn + j*16 + l15)*32 + quad*8];
    #pragma unroll
    for (int i = 0; i < 4; i++)
      #pragma unroll
      for (int j = 0; j < 4; j++)
        acc[i][j] = __builtin_amdgcn_mfma_f32_16x16x32_bf16(af[i], bfr[j], acc[i][j], 0, 0, 0);
  }

  #pragma unroll
  for (int i = 0; i < 4; i++) {
    #pragma unroll
    for (int j = 0; j < 4; j++) {
      int ncol = n0 + wn + j*16 + l15;
      float bv = bias[ncol];
      #pragma unroll
      for (int r = 0; r < 4; r++) {
        int m = m0 + wm + i*16 + quad*4 + r;   // C/D: row=(lane>>4)*4+reg, col=lane&15
        float val = (acc[i][j][r] + bv) * scale;
        if (mode == 0) {
          ((float*)outp)[m*512 + ncol] = val;
        } else {
          int bb = m >> 10, l = m & 1023, hh = ncol >> 6, d = ncol & 63;
          u16 o = f2bf(val);
          if (mode == 1) ((u16*)outp)[((bb*8 + hh)*1024 + l)*64 + d] = o;
          else           ((u16*)outp)[((bb*8 + hh)*64 + d)*1024 + l] = o;
        }
      }
    }
  }
}

// ---------------- fused attention, barrier-free k-loop ----------------
// grid 512: b = blockIdx&7 (XCD L2 locality), qt = blockIdx>>3.
// Block = 16 q-rows x 8 heads x 1024 keys; wave w owns heads {w, w+4}.
// rel data pre-packed (k_pack) and read per-lane from global exactly once per
// block -> the k-loop has ZERO __syncthreads (R3's 64 barriers + 2 blocks/CU
// were the stall: all waves drained together every tile).
// Far/band split: only <=3 of 32 k-tiles intersect the +-32 band; far tiles
// use register qd0/qd64 and skip PB writes / bucket math entirely.
__global__ __launch_bounds__(256, 2) void k_attn(
    const u16* __restrict__ qws, const u16* __restrict__ kws, const u16* __restrict__ vtws,
    const u16* __restrict__ relk80, const u16* __restrict__ relvT,
    const float* __restrict__ tree_emb, const u32* __restrict__ packed,
    float* __restrict__ ctx) {
  __shared__ u16 qdotL[8*16*68];    // [h][q][bucket]  (band phase only)
  __shared__ u16 PB[8][16*96];      // per-head banded P
  __shared__ u16 Pl[4][2][16*40];   // per-wave C->A bridge, stride 40 (16B-aligned rows)
  __shared__ u32 treecP[256];       // [vocab][w]: lo=head w, hi=head w+4 (bf16)

  int tid = threadIdx.x, lane = tid & 63, wv = tid >> 6;
  int quad = lane >> 4, l15 = lane & 15;
  int b = blockIdx.x & 7, qt = blockIdx.x >> 3;
  int q0 = qt * 16;

  if (tid < 256) {
    int v = tid >> 2, w2 = tid & 3;
    treecP[v*4 + w2] = (u32)f2bf(tree_emb[v*8 + w2]) | ((u32)f2bf(tree_emb[v*8 + w2 + 4]) << 16);
  }
  for (int i = tid; i < 8*16*96/2; i += 256) ((u32*)PB)[i] = 0u;

  const u16* qb[2] = { qws + (size_t)(b*8 + wv)*(1024*64),
                       qws + (size_t)(b*8 + wv + 4)*(1024*64) };
  const u16* kb[2] = { kws + (size_t)(b*8 + wv)*(1024*64),
                       kws + (size_t)(b*8 + wv + 4)*(1024*64) };
  const u16* vb[2] = { vtws + (size_t)(b*8 + wv)*(64*1024),
                       vtws + (size_t)(b*8 + wv + 4)*(64*1024) };
  const u32* pkb = packed + ((size_t)b << 20);

  // Q fragments (A-layout), q pre-scaled by 1/8
  short8 aQ[2][2];
  #pragma unroll
  for (int h2 = 0; h2 < 2; h2++)
    #pragma unroll
    for (int kf = 0; kf < 2; kf++)
      aQ[h2][kf] = *(const short8*)(qb[h2] + (q0 + l15)*64 + kf*32 + quad*8);

  // qdot = q . rel_emb_k[bucket]; capture bucket-0/64 rows into regs via shfl
  float qd0[2][4], qd64[2][4];
  #pragma unroll
  for (int h2 = 0; h2 < 2; h2++) {
    #pragma unroll
    for (int t = 0; t < 5; t++) {
      f32x4 C = (f32x4){0.f,0.f,0.f,0.f};
      #pragma unroll
      for (int kf = 0; kf < 2; kf++) {
        short8 bR = *(const short8*)(relk80 + (t*16 + l15)*64 + kf*32 + quad*8);
        C = __builtin_amdgcn_mfma_f32_16x16x32_bf16(aQ[h2][kf], bR, C, 0, 0, 0);
      }
      if (t == 0) {
        #pragma unroll
        for (int r = 0; r < 4; r++) qd0[h2][r] = __shfl(C[r], lane & 48, 64);
      }
      if (t == 4) {
        #pragma unroll
        for (int r = 0; r < 4; r++) qd64[h2][r] = __shfl(C[r], lane & 48, 64);
      }
      int col = t*16 + l15;
      if (col < 65) {
        #pragma unroll
        for (int r = 0; r < 4; r++)
          qdotL[((wv + h2*4)*16 + quad*4 + r)*68 + col] = f2bf(C[r]);
      }
    }
  }
  __syncthreads();   // treecP (cross-wave) ready; qdotL/PB are per-owner-wave

  int t_lo = max(0, (q0 - 31) >> 5);        // tiles < t_lo: all d <= -32
  int t_hi = min(31, (q0 + 46) >> 5);       // tiles > t_hi: all d >= 32

  // prefetch tile 0: K frags + packed rel
  short8 kreg[2][2][2];
  #pragma unroll
  for (int h2 = 0; h2 < 2; h2++)
    #pragma unroll
    for (int ct = 0; ct < 2; ct++)
      #pragma unroll
      for (int kf = 0; kf < 2; kf++)
        kreg[h2][ct][kf] = *(const short8*)(kb[h2] + (ct*16 + l15)*64 + kf*32 + quad*8);
  u32 pk[8];
  #pragma unroll
  for (int e = 0; e < 8; e++) {
    int ct = e >> 2, r = e & 3;
    pk[e] = pkb[((q0 + quad*4 + r) << 10) + ct*16 + l15];
  }

  f32x4 O[2][4];
  float rs[2][4], ts0[2][4], ts1[2][4];
  #pragma unroll
  for (int h2 = 0; h2 < 2; h2++) {
    #pragma unroll
    for (int t = 0; t < 4; t++) O[h2][t] = (f32x4){0.f,0.f,0.f,0.f};
    #pragma unroll
    for (int r = 0; r < 4; r++) { rs[h2][r] = 0.f; ts0[h2][r] = 0.f; ts1[h2][r] = 0.f; }
  }

  for (int it = 0; it < 32; ++it) {
    int k0 = it << 5;
    int kn = (it + 1 < 32) ? (k0 + 32) : 0;   // wrap: valid addr, values unused
    // V for current tile (issued early, consumed last)
    short8 vreg[2][4];
    #pragma unroll
    for (int h2 = 0; h2 < 2; h2++)
      #pragma unroll
      for (int t = 0; t < 4; t++)
        vreg[h2][t] = *(const short8*)(vb[h2] + (t*16 + l15)*1024 + k0 + quad*8);

    // QK^T from prefetched K
    f32x4 S[2][2];
    #pragma unroll
    for (int h2 = 0; h2 < 2; h2++)
      #pragma unroll
      for (int ct = 0; ct < 2; ct++) {
        f32x4 c = (f32x4){0.f,0.f,0.f,0.f};
        #pragma unroll
        for (int kf = 0; kf < 2; kf++)
          c = __builtin_amdgcn_mfma_f32_16x16x32_bf16(aQ[h2][kf], kreg[h2][ct][kf], c, 0, 0, 0);
        S[h2][ct] = c;
      }
    // prefetch next K + packed
    #pragma unroll
    for (int h2 = 0; h2 < 2; h2++)
      #pragma unroll
      for (int ct = 0; ct < 2; ct++)
        #pragma unroll
        for (int kf = 0; kf < 2; kf++)
          kreg[h2][ct][kf] = *(const short8*)(kb[h2] + (kn + ct*16 + l15)*64 + kf*32 + quad*8);
    u32 pkc[8];
    #pragma unroll
    for (int e = 0; e < 8; e++) pkc[e] = pk[e];
    #pragma unroll
    for (int e = 0; e < 8; e++) {
      int ct = e >> 2, r = e & 3;
      pk[e] = pkb[((q0 + quad*4 + r) << 10) + kn + ct*16 + l15];
    }

    if (it < t_lo || it > t_hi) {
      // -------- far tile: constant bucket (0 or 64), no PB writes --------
      bool pre = it < t_lo;
      #pragma unroll
      for (int ct = 0; ct < 2; ct++) {
        #pragma unroll
        for (int r = 0; r < 4; r++) {
          u32 sg = pkc[ct*4 + r];
          float rw = bf2f((u16)(sg >> 16));
          float mb = (sg & 128u) ? -1e30f : 0.f;
          u32 tp = treecP[(sg & 63u)*4 + wv];
          #pragma unroll
          for (int h2 = 0; h2 < 2; h2++) {
            float tb = bf2f((u16)(h2 ? (tp >> 16) : (tp & 0xffffu)));
            float qv = pre ? qd0[h2][r] : qd64[h2][r];
            float p = __expf(S[h2][ct][r] + qv + tb*rw + mb);
            rs[h2][r]  += p;
            ts0[h2][r] += pre ? p : 0.f;
            ts1[h2][r] += pre ? 0.f : p;
            Pl[wv][h2][(quad*4 + r)*40 + ct*16 + l15] = f2bf(p);
          }
        }
      }
    } else {
      // -------- band tile: general path --------
      #pragma unroll
      for (int ct = 0; ct < 2; ct++) {
        #pragma unroll
        for (int r = 0; r < 4; r++) {
          int kloc = ct*16 + l15, qloc = quad*4 + r;
          int d = (k0 + kloc) - (q0 + qloc);
          int bucket = min(max(d + 32, 0), 64);
          u32 sg = pkc[ct*4 + r];
          float rw = bf2f((u16)(sg >> 16));
          float mb = (sg & 128u) ? -1e30f : 0.f;
          u32 tp = treecP[(sg & 63u)*4 + wv];
          #pragma unroll
          for (int h2 = 0; h2 < 2; h2++) {
            float qd = bf2f(qdotL[((wv + h2*4)*16 + qloc)*68 + bucket]);
            float tb = bf2f((u16)(h2 ? (tp >> 16) : (tp & 0xffffu)));
            float p = __expf(S[h2][ct][r] + qd + tb*rw + mb);
            rs[h2][r] += p;
            if (d <= -32)      ts0[h2][r] += p;
            else if (d >= 32)  ts1[h2][r] += p;
            else               PB[wv + h2*4][qloc*96 + d + 32] = f2bf(p);
            Pl[wv][h2][qloc*40 + kloc] = f2bf(p);
          }
        }
      }
    }

    // PV (Pl bridge: C-layout -> A-layout, per-wave, no barrier)
    #pragma unroll
    for (int h2 = 0; h2 < 2; h2++) {
      short8 aP = *(const short8*)&Pl[wv][h2][l15*40 + quad*8];
      #pragma unroll
      for (int t = 0; t < 4; t++)
        O[h2][t] = __builtin_amdgcn_mfma_f32_16x16x32_bf16(aP, vreg[h2][t], O[h2][t], 0, 0, 0);
    }
  }

  // row sums across the 16 lanes of each quad-group
  #pragma unroll
  for (int m = 1; m < 16; m <<= 1) {
    #pragma unroll
    for (int h2 = 0; h2 < 2; h2++)
      #pragma unroll
      for (int r = 0; r < 4; r++) {
        rs[h2][r]  += __shfl_xor(rs[h2][r],  m, 64);
        ts0[h2][r] += __shfl_xor(ts0[h2][r], m, 64);
        ts1[h2][r] += __shfl_xor(ts1[h2][r], m, 64);
      }
  }
  if (l15 == 0) {
    #pragma unroll
    for (int h2 = 0; h2 < 2; h2++)
      #pragma unroll
      for (int r = 0; r < 4; r++) {
        PB[wv + h2*4][(quad*4 + r)*96 + 0]  = f2bf(ts0[h2][r]);
        PB[wv + h2*4][(quad*4 + r)*96 + 64] = f2bf(ts1[h2][r]);
      }
  }
  __syncthreads();

  // rel_v: PB[16,96] @ relvT^T
  #pragma unroll
  for (int h2 = 0; h2 < 2; h2++) {
    short8 aB[3];
    #pragma unroll
    for (int s = 0; s < 3; s++)
      aB[s] = *(const short8*)&PB[wv + h2*4][l15*96 + s*32 + quad*8];
    #pragma unroll
    for (int t = 0; t < 4; t++)
      #pragma unroll
      for (int s = 0; s < 3; s++) {
        short8 bRV = *(const short8*)(relvT + (t*16 + l15)*96 + s*32 + quad*8);
        O[h2][t] = __builtin_amdgcn_mfma_f32_16x16x32_bf16(aB[s], bRV, O[h2][t], 0, 0, 0);
      }
  }

  #pragma unroll
  for (int h2 = 0; h2 < 2; h2++) {
    float inv[4];
    #pragma unroll
    for (int r = 0; r < 4; r++) inv[r] = 1.0f / rs[h2][r];
    #pragma unroll
    for (int t = 0; t < 4; t++)
      #pragma unroll
      for (int r = 0; r < 4; r++) {
        int qg = q0 + quad*4 + r;
        ctx[(b*1024 + qg)*512 + (wv + h2*4)*64 + t*16 + l15] = O[h2][t][r] * inv[r];
      }
  }
}

extern "C" void kernel_launch(void* const* d_in, const int* in_sizes, int n_in,
                              void* d_out, int out_size, void* d_ws, size_t ws_size,
                              hipStream_t stream) {
  const float* key   = (const float*)d_in[0];
  const float* value = (const float*)d_in[1];
  const float* query = (const float*)d_in[2];
  const unsigned char* maskp = (const unsigned char*)d_in[3];
  const int*   relm  = (const int*)d_in[4];
  const float* relw  = (const float*)d_in[5];
  const float* Wk = (const float*)d_in[6];
  const float* bk = (const float*)d_in[7];
  const float* Wq = (const float*)d_in[8];
  const float* bq = (const float*)d_in[9];
  const float* Wv = (const float*)d_in[10];
  const float* bv = (const float*)d_in[11];
  const float* Wo = (const float*)d_in[12];
  const float* bo = (const float*)d_in[13];
  const float* rek = (const float*)d_in[14];
  const float* rev = (const float*)d_in[15];
  const float* te  = (const float*)d_in[16];
  (void)in_sizes; (void)n_in; (void)out_size;

  char* w = (char*)d_ws;
  size_t off = 0;
  auto alloc = [&](size_t bytes) -> void* {
    void* p = w + off; off += (bytes + 255) & ~(size_t)255; return p;
  };
  u16* WkT = (u16*)alloc((size_t)512*512*2);
  u16* WqT = (u16*)alloc((size_t)512*512*2);
  u16* WvT = (u16*)alloc((size_t)512*512*2);
  u16* WoT = (u16*)alloc((size_t)512*512*2);
  u16* qws = (u16*)alloc((size_t)8*8*1024*64*2);   // [B,H,L,64], pre-scaled 1/8
  u16* kws = (u16*)alloc((size_t)8*8*1024*64*2);   // [B,H,L,64]
  u16* vt  = (u16*)alloc((size_t)8*8*1024*64*2);   // [B,H,64,L]
  float* ctxb = (float*)alloc((size_t)8192*512*4); // [B,L,512] fp32
  u32* packed = (u32*)alloc((size_t)8*1024*1024*4);
  u16* relk80 = (u16*)alloc((size_t)80*64*2);
  u16* relvT  = (u16*)alloc((size_t)64*96*2);
  if (off > ws_size) return;

  k_wt4<<<dim3(16,16,4), 256, 0, stream>>>(Wk, Wq, Wv, Wo, WkT, WqT, WvT, WoT);
  k_prep_rel<<<44, 256, 0, stream>>>(rek, rev, relk80, relvT);
  k_pack<<<8192, 256, 0, stream>>>(relm, relw, maskp, packed);

  dim3 gg(4, 64);
  k_gemm<<<gg, 256, 0, stream>>>(query, WqT, bq, (void*)qws, 1, 0.125f);
  k_gemm<<<gg, 256, 0, stream>>>(key,   WkT, bk, (void*)kws, 1, 1.0f);
  k_gemm<<<gg, 256, 0, stream>>>(value, WvT, bv, (void*)vt,  2, 1.0f);

  k_attn<<<512, 256, 0, stream>>>(qws, kws, vt, relk80, relvT, te, packed, ctxb);

  k_gemm<<<gg, 256, 0, stream>>>(ctxb, WoT, bo, d_out, 0, 1.0f);
}

// Round 5
// 385.507 us; speedup vs baseline: 1.0881x; 1.0881x over previous
//
#include <hip/hip_runtime.h>
#include <stdint.h>

using f32x4  = __attribute__((ext_vector_type(4))) float;
using short8 = __attribute__((ext_vector_type(8))) short;
typedef unsigned short u16;
typedef unsigned int   u32;

// B=8, H=8, L=1024, DM=512, DK=DV=64.  M = B*L = 8192.

static __device__ __forceinline__ u16 f2bf(float f) {
  union { float f; u32 u; } v; v.f = f;
  u32 r = v.u + 0x7fffu + ((v.u >> 16) & 1u);   // RNE
  return (u16)(r >> 16);
}
static __device__ __forceinline__ float bf2f(u16 u) {
  union { u32 u; float f; } v; v.u = ((u32)u) << 16;
  return v.f;
}

// async global->LDS, 16B per lane; LDS dest = wave-uniform base + lane*16
#define GLDS16(g, l) __builtin_amdgcn_global_load_lds( \
    (const __attribute__((address_space(1))) u32*)(g), \
    (__attribute__((address_space(3))) u32*)(l), 16, 0, 0)

// ------- 4 weight transposes in one launch: W [512k][512n] -> Wt [n][k] bf16
__global__ __launch_bounds__(256) void k_wt4(const float* __restrict__ W0, const float* __restrict__ W1,
                                             const float* __restrict__ W2, const float* __restrict__ W3,
                                             u16* __restrict__ T0, u16* __restrict__ T1,
                                             u16* __restrict__ T2, u16* __restrict__ T3) {
  const float* W = (blockIdx.z == 0) ? W0 : (blockIdx.z == 1) ? W1 : (blockIdx.z == 2) ? W2 : W3;
  u16* T = (blockIdx.z == 0) ? T0 : (blockIdx.z == 1) ? T1 : (blockIdx.z == 2) ? T2 : T3;
  __shared__ float t[32][33];
  int tx = threadIdx.x & 31, ty = threadIdx.x >> 5;   // 32 x 8
  int x0 = blockIdx.x * 32, y0 = blockIdx.y * 32;     // x = n, y = k
  #pragma unroll
  for (int i = 0; i < 4; i++)
    t[ty + i*8][tx] = W[(y0 + ty + i*8) * 512 + (x0 + tx)];
  __syncthreads();
  #pragma unroll
  for (int i = 0; i < 4; i++)
    T[(x0 + ty + i*8) * 512 + (y0 + tx)] = f2bf(t[tx][ty + i*8]);
}

// ------------- rel embeddings: relk80 [80][64] (zero-pad rows>=65),
//               relvT [64 dv][96 bucket] (zero-pad buckets>=65) -------------
__global__ __launch_bounds__(256) void k_prep_rel(const float* __restrict__ rk,
                                                  const float* __restrict__ rv,
                                                  u16* __restrict__ relk80,
                                                  u16* __restrict__ relvT) {
  int i = blockIdx.x * 256 + threadIdx.x;
  if (i < 80*64) {
    int row = i >> 6;
    relk80[i] = (row < 65) ? f2bf(rk[i]) : (u16)0;
  }
  int j = i - 80*64;
  if (j >= 0 && j < 64*96) {
    int dv = j / 96, bk = j % 96;
    relvT[j] = (bk < 65) ? f2bf(rv[bk*64 + dv]) : (u16)0;
  }
}

// ------------- fp32 -> bf16 for query/key/value in one launch -------------
__global__ __launch_bounds__(256) void k_cvt3(const float* __restrict__ a, const float* __restrict__ b,
                                              const float* __restrict__ c,
                                              u16* __restrict__ oa, u16* __restrict__ ob,
                                              u16* __restrict__ oc) {
  const float* src = (blockIdx.y == 0) ? a : (blockIdx.y == 1) ? b : c;
  u16* dst = (blockIdx.y == 0) ? oa : (blockIdx.y == 1) ? ob : oc;
  int i = blockIdx.x * 256 + threadIdx.x;
  float4 v = ((const float4*)src)[i];
  ushort4 o;
  o.x = f2bf(v.x); o.y = f2bf(v.y); o.z = f2bf(v.z); o.w = f2bf(v.w);
  ((ushort4*)dst)[i] = o;
}

// ------------- pack rel_matrix | mask<<7 | bf16(rel_mask)<<16 -> u32 -------
__global__ __launch_bounds__(256) void k_pack(const int* __restrict__ rm,
                                              const float* __restrict__ rw,
                                              const unsigned char* __restrict__ mk,
                                              u32* __restrict__ outp) {
  int i = blockIdx.x * 256 + threadIdx.x;     // x4 elements
  int4   r4 = ((const int4*)rm)[i];
  float4 w4 = ((const float4*)rw)[i];
  uchar4 m4 = ((const uchar4*)mk)[i];
  uint4 o;
  o.x = (u32)(r4.x & 63) | (m4.x ? 128u : 0u) | ((u32)f2bf(w4.x) << 16);
  o.y = (u32)(r4.y & 63) | (m4.y ? 128u : 0u) | ((u32)f2bf(w4.y) << 16);
  o.z = (u32)(r4.z & 63) | (m4.z ? 128u : 0u) | ((u32)f2bf(w4.z) << 16);
  o.w = (u32)(r4.w & 63) | (m4.w ? 128u : 0u) | ((u32)f2bf(w4.w) << 16);
  ((uint4*)outp)[i] = o;
}

// ---------------- bf16 MFMA GEMM (m97-style): C = A[8192,512] @ Wt^T + bias
// A bf16 row-major, Wt [n][k] bf16.  Tile M=128, N=64, BK=32; grid (8,64,z).
// Staging via global_load_lds width=16 (no VGPR round-trip, no VALU cvt).
// mode 0: fp32 out [m][n];  mode 1: bf16 [b,h,l,d];  mode 2: bf16 [b,h,d,l].
struct GArg { const u16* A; const u16* Wt; const float* bias; void* out; int mode; float scale; };

__global__ __launch_bounds__(256) void k_gemm(GArg g0, GArg g1, GArg g2) {
  GArg ar = (blockIdx.z == 0) ? g0 : (blockIdx.z == 1) ? g1 : g2;
  __shared__ u16 As[128*32];   // chunk c (16B) at byte c*16: row=c>>2, 16B-slot=c&3
  __shared__ u16 Bs[64*32];
  int tid = threadIdx.x, lane = tid & 63, wv = tid >> 6;
  int quad = lane >> 4, l15 = lane & 15;
  int n0 = blockIdx.x * 64, m0 = blockIdx.y * 128;
  int wm = (wv >> 1) * 64, wn = (wv & 1) * 32;
  f32x4 acc[4][2];
  #pragma unroll
  for (int i = 0; i < 4; i++)
    #pragma unroll
    for (int j = 0; j < 2; j++)
      acc[i][j] = (f32x4){0.f, 0.f, 0.f, 0.f};

  const u16* Abase = ar.A  + (size_t)m0 * 512;
  const u16* Bbase = ar.Wt + (size_t)n0 * 512;
  int cA0 = wv * 128, cB0 = wv * 64;      // wave-uniform chunk bases

  for (int k0 = 0; k0 < 512; k0 += 32) {
    #pragma unroll
    for (int i = 0; i < 2; i++) {
      int c = cA0 + i*64 + lane;
      GLDS16(Abase + (c >> 2)*512 + k0 + (c & 3)*8, &As[(cA0 + i*64)*8]);
    }
    {
      int c = cB0 + lane;
      GLDS16(Bbase + (c >> 2)*512 + k0 + (c & 3)*8, &Bs[cB0*8]);
    }
    __syncthreads();   // drains vmcnt (incl. global_load_lds) before LDS reads
    short8 af[4], bf[2];
    #pragma unroll
    for (int i = 0; i < 4; i++) af[i] = *(const short8*)&As[(wm + i*16 + l15)*32 + quad*8];
    #pragma unroll
    for (int j = 0; j < 2; j++) bf[j] = *(const short8*)&Bs[(wn + j*16 + l15)*32 + quad*8];
    #pragma unroll
    for (int i = 0; i < 4; i++)
      #pragma unroll
      for (int j = 0; j < 2; j++)
        acc[i][j] = __builtin_amdgcn_mfma_f32_16x16x32_bf16(af[i], bf[j], acc[i][j], 0, 0, 0);
    __syncthreads();   // protect LDS before next stage
  }

  #pragma unroll
  for (int i = 0; i < 4; i++) {
    #pragma unroll
    for (int j = 0; j < 2; j++) {
      int ncol = n0 + wn + j*16 + l15;
      float bv = ar.bias[ncol];
      #pragma unroll
      for (int r = 0; r < 4; r++) {
        int m = m0 + wm + i*16 + quad*4 + r;   // C/D: row=(lane>>4)*4+reg, col=lane&15
        float val = (acc[i][j][r] + bv) * ar.scale;
        if (ar.mode == 0) {
          ((float*)ar.out)[m*512 + ncol] = val;
        } else {
          int bb = m >> 10, l = m & 1023, hh = ncol >> 6, d = ncol & 63;
          u16 o = f2bf(val);
          if (ar.mode == 1) ((u16*)ar.out)[((bb*8 + hh)*1024 + l)*64 + d] = o;
          else              ((u16*)ar.out)[((bb*8 + hh)*64 + d)*1024 + l] = o;
        }
      }
    }
  }
}

// ---------------- fused attention, barrier-free k-loop ----------------
// grid 512: b = blockIdx&7 (XCD L2 locality), qt = blockIdx>>3.
// Block = 16 q-rows x 8 heads x 1024 keys; wave w owns heads {w, w+4}.
// rel data pre-packed (k_pack), read per-lane from global exactly once per
// block; the k-loop has zero __syncthreads.  Far/band split: only <=3 of 32
// k-tiles intersect the +-32 band.
__global__ __launch_bounds__(256, 2) void k_attn(
    const u16* __restrict__ qws, const u16* __restrict__ kws, const u16* __restrict__ vtws,
    const u16* __restrict__ relk80, const u16* __restrict__ relvT,
    const float* __restrict__ tree_emb, const u32* __restrict__ packed,
    u16* __restrict__ ctx) {
  __shared__ u16 qdotL[8*16*68];    // [h][q][bucket]  (band phase only)
  __shared__ u16 PB[8][16*96];      // per-head banded P
  __shared__ u16 Pl[4][2][16*40];   // per-wave C->A bridge, stride 40
  __shared__ u32 treecP[256];       // [vocab][w]: lo=head w, hi=head w+4 (bf16)

  int tid = threadIdx.x, lane = tid & 63, wv = tid >> 6;
  int quad = lane >> 4, l15 = lane & 15;
  int b = blockIdx.x & 7, qt = blockIdx.x >> 3;
  int q0 = qt * 16;

  if (tid < 256) {
    int v = tid >> 2, w2 = tid & 3;
    treecP[v*4 + w2] = (u32)f2bf(tree_emb[v*8 + w2]) | ((u32)f2bf(tree_emb[v*8 + w2 + 4]) << 16);
  }
  for (int i = tid; i < 8*16*96/2; i += 256) ((u32*)PB)[i] = 0u;

  const u16* qb[2] = { qws + (size_t)(b*8 + wv)*(1024*64),
                       qws + (size_t)(b*8 + wv + 4)*(1024*64) };
  const u16* kb[2] = { kws + (size_t)(b*8 + wv)*(1024*64),
                       kws + (size_t)(b*8 + wv + 4)*(1024*64) };
  const u16* vb[2] = { vtws + (size_t)(b*8 + wv)*(64*1024),
                       vtws + (size_t)(b*8 + wv + 4)*(64*1024) };
  const u32* pkb = packed + ((size_t)b << 20);

  // Q fragments (A-layout), q pre-scaled by 1/8
  short8 aQ[2][2];
  #pragma unroll
  for (int h2 = 0; h2 < 2; h2++)
    #pragma unroll
    for (int kf = 0; kf < 2; kf++)
      aQ[h2][kf] = *(const short8*)(qb[h2] + (q0 + l15)*64 + kf*32 + quad*8);

  // qdot = q . rel_emb_k[bucket]; capture bucket-0/64 rows into regs via shfl
  float qd0[2][4], qd64[2][4];
  #pragma unroll
  for (int h2 = 0; h2 < 2; h2++) {
    #pragma unroll
    for (int t = 0; t < 5; t++) {
      f32x4 C = (f32x4){0.f,0.f,0.f,0.f};
      #pragma unroll
      for (int kf = 0; kf < 2; kf++) {
        short8 bR = *(const short8*)(relk80 + (t*16 + l15)*64 + kf*32 + quad*8);
        C = __builtin_amdgcn_mfma_f32_16x16x32_bf16(aQ[h2][kf], bR, C, 0, 0, 0);
      }
      if (t == 0) {
        #pragma unroll
        for (int r = 0; r < 4; r++) qd0[h2][r] = __shfl(C[r], lane & 48, 64);
      }
      if (t == 4) {
        #pragma unroll
        for (int r = 0; r < 4; r++) qd64[h2][r] = __shfl(C[r], lane & 48, 64);
      }
      int col = t*16 + l15;
      if (col < 65) {
        #pragma unroll
        for (int r = 0; r < 4; r++)
          qdotL[((wv + h2*4)*16 + quad*4 + r)*68 + col] = f2bf(C[r]);
      }
    }
  }
  __syncthreads();   // treecP (cross-wave) ready

  int t_lo = max(0, (q0 - 31) >> 5);        // tiles < t_lo: all d <= -32
  int t_hi = min(31, (q0 + 46) >> 5);       // tiles > t_hi: all d >= 32

  // prefetch tile 0: K frags + packed rel
  short8 kreg[2][2][2];
  #pragma unroll
  for (int h2 = 0; h2 < 2; h2++)
    #pragma unroll
    for (int ct = 0; ct < 2; ct++)
      #pragma unroll
      for (int kf = 0; kf < 2; kf++)
        kreg[h2][ct][kf] = *(const short8*)(kb[h2] + (ct*16 + l15)*64 + kf*32 + quad*8);
  u32 pk[8];
  #pragma unroll
  for (int e = 0; e < 8; e++) {
    int ct = e >> 2, r = e & 3;
    pk[e] = pkb[((q0 + quad*4 + r) << 10) + ct*16 + l15];
  }

  f32x4 O[2][4];
  float rs[2][4], ts0[2][4], ts1[2][4];
  #pragma unroll
  for (int h2 = 0; h2 < 2; h2++) {
    #pragma unroll
    for (int t = 0; t < 4; t++) O[h2][t] = (f32x4){0.f,0.f,0.f,0.f};
    #pragma unroll
    for (int r = 0; r < 4; r++) { rs[h2][r] = 0.f; ts0[h2][r] = 0.f; ts1[h2][r] = 0.f; }
  }

  for (int it = 0; it < 32; ++it) {
    int k0 = it << 5;
    int kn = (it + 1 < 32) ? (k0 + 32) : 0;   // wrap: valid addr, values unused
    short8 vreg[2][4];
    #pragma unroll
    for (int h2 = 0; h2 < 2; h2++)
      #pragma unroll
      for (int t = 0; t < 4; t++)
        vreg[h2][t] = *(const short8*)(vb[h2] + (t*16 + l15)*1024 + k0 + quad*8);

    f32x4 S[2][2];
    #pragma unroll
    for (int h2 = 0; h2 < 2; h2++)
      #pragma unroll
      for (int ct = 0; ct < 2; ct++) {
        f32x4 c = (f32x4){0.f,0.f,0.f,0.f};
        #pragma unroll
        for (int kf = 0; kf < 2; kf++)
          c = __builtin_amdgcn_mfma_f32_16x16x32_bf16(aQ[h2][kf], kreg[h2][ct][kf], c, 0, 0, 0);
        S[h2][ct] = c;
      }
    #pragma unroll
    for (int h2 = 0; h2 < 2; h2++)
      #pragma unroll
      for (int ct = 0; ct < 2; ct++)
        #pragma unroll
        for (int kf = 0; kf < 2; kf++)
          kreg[h2][ct][kf] = *(const short8*)(kb[h2] + (kn + ct*16 + l15)*64 + kf*32 + quad*8);
    u32 pkc[8];
    #pragma unroll
    for (int e = 0; e < 8; e++) pkc[e] = pk[e];
    #pragma unroll
    for (int e = 0; e < 8; e++) {
      int ct = e >> 2, r = e & 3;
      pk[e] = pkb[((q0 + quad*4 + r) << 10) + kn + ct*16 + l15];
    }

    if (it < t_lo || it > t_hi) {
      bool pre = it < t_lo;
      #pragma unroll
      for (int ct = 0; ct < 2; ct++) {
        #pragma unroll
        for (int r = 0; r < 4; r++) {
          u32 sg = pkc[ct*4 + r];
          float rw = bf2f((u16)(sg >> 16));
          float mb = (sg & 128u) ? -1e30f : 0.f;
          u32 tp = treecP[(sg & 63u)*4 + wv];
          #pragma unroll
          for (int h2 = 0; h2 < 2; h2++) {
            float tb = bf2f((u16)(h2 ? (tp >> 16) : (tp & 0xffffu)));
            float qv = pre ? qd0[h2][r] : qd64[h2][r];
            float p = __expf(S[h2][ct][r] + qv + tb*rw + mb);
            rs[h2][r]  += p;
            ts0[h2][r] += pre ? p : 0.f;
            ts1[h2][r] += pre ? 0.f : p;
            Pl[wv][h2][(quad*4 + r)*40 + ct*16 + l15] = f2bf(p);
          }
        }
      }
    } else {
      #pragma unroll
      for (int ct = 0; ct < 2; ct++) {
        #pragma unroll
        for (int r = 0; r < 4; r++) {
          int kloc = ct*16 + l15, qloc = quad*4 + r;
          int d = (k0 + kloc) - (q0 + qloc);
          int bucket = min(max(d + 32, 0), 64);
          u32 sg = pkc[ct*4 + r];
          float rw = bf2f((u16)(sg >> 16));
          float mb = (sg & 128u) ? -1e30f : 0.f;
          u32 tp = treecP[(sg & 63u)*4 + wv];
          #pragma unroll
          for (int h2 = 0; h2 < 2; h2++) {
            float qd = bf2f(qdotL[((wv + h2*4)*16 + qloc)*68 + bucket]);
            float tb = bf2f((u16)(h2 ? (tp >> 16) : (tp & 0xffffu)));
            float p = __expf(S[h2][ct][r] + qd + tb*rw + mb);
            rs[h2][r] += p;
            if (d <= -32)      ts0[h2][r] += p;
            else if (d >= 32)  ts1[h2][r] += p;
            else               PB[wv + h2*4][qloc*96 + d + 32] = f2bf(p);
            Pl[wv][h2][qloc*40 + kloc] = f2bf(p);
          }
        }
      }
    }

    #pragma unroll
    for (int h2 = 0; h2 < 2; h2++) {
      short8 aP = *(const short8*)&Pl[wv][h2][l15*40 + quad*8];
      #pragma unroll
      for (int t = 0; t < 4; t++)
        O[h2][t] = __builtin_amdgcn_mfma_f32_16x16x32_bf16(aP, vreg[h2][t], O[h2][t], 0, 0, 0);
    }
  }

  #pragma unroll
  for (int m = 1; m < 16; m <<= 1) {
    #pragma unroll
    for (int h2 = 0; h2 < 2; h2++)
      #pragma unroll
      for (int r = 0; r < 4; r++) {
        rs[h2][r]  += __shfl_xor(rs[h2][r],  m, 64);
        ts0[h2][r] += __shfl_xor(ts0[h2][r], m, 64);
        ts1[h2][r] += __shfl_xor(ts1[h2][r], m, 64);
      }
  }
  if (l15 == 0) {
    #pragma unroll
    for (int h2 = 0; h2 < 2; h2++)
      #pragma unroll
      for (int r = 0; r < 4; r++) {
        PB[wv + h2*4][(quad*4 + r)*96 + 0]  = f2bf(ts0[h2][r]);
        PB[wv + h2*4][(quad*4 + r)*96 + 64] = f2bf(ts1[h2][r]);
      }
  }
  __syncthreads();

  // rel_v: PB[16,96] @ relvT^T
  #pragma unroll
  for (int h2 = 0; h2 < 2; h2++) {
    short8 aB[3];
    #pragma unroll
    for (int s = 0; s < 3; s++)
      aB[s] = *(const short8*)&PB[wv + h2*4][l15*96 + s*32 + quad*8];
    #pragma unroll
    for (int t = 0; t < 4; t++)
      #pragma unroll
      for (int s = 0; s < 3; s++) {
        short8 bRV = *(const short8*)(relvT + (t*16 + l15)*96 + s*32 + quad*8);
        O[h2][t] = __builtin_amdgcn_mfma_f32_16x16x32_bf16(aB[s], bRV, O[h2][t], 0, 0, 0);
      }
  }

  #pragma unroll
  for (int h2 = 0; h2 < 2; h2++) {
    float inv[4];
    #pragma unroll
    for (int r = 0; r < 4; r++) inv[r] = 1.0f / rs[h2][r];
    #pragma unroll
    for (int t = 0; t < 4; t++)
      #pragma unroll
      for (int r = 0; r < 4; r++) {
        int qg = q0 + quad*4 + r;
        ctx[(b*1024 + qg)*512 + (wv + h2*4)*64 + t*16 + l15] = f2bf(O[h2][t][r] * inv[r]);
      }
  }
}

extern "C" void kernel_launch(void* const* d_in, const int* in_sizes, int n_in,
                              void* d_out, int out_size, void* d_ws, size_t ws_size,
                              hipStream_t stream) {
  const float* key   = (const float*)d_in[0];
  const float* value = (const float*)d_in[1];
  const float* query = (const float*)d_in[2];
  const unsigned char* maskp = (const unsigned char*)d_in[3];
  const int*   relm  = (const int*)d_in[4];
  const float* relw  = (const float*)d_in[5];
  const float* Wk = (const float*)d_in[6];
  const float* bk = (const float*)d_in[7];
  const float* Wq = (const float*)d_in[8];
  const float* bq = (const float*)d_in[9];
  const float* Wv = (const float*)d_in[10];
  const float* bv = (const float*)d_in[11];
  const float* Wo = (const float*)d_in[12];
  const float* bo = (const float*)d_in[13];
  const float* rek = (const float*)d_in[14];
  const float* rev = (const float*)d_in[15];
  const float* te  = (const float*)d_in[16];
  (void)in_sizes; (void)n_in; (void)out_size;

  char* w = (char*)d_ws;
  size_t off = 0;
  auto alloc = [&](size_t bytes) -> void* {
    void* p = w + off; off += (bytes + 255) & ~(size_t)255; return p;
  };
  u16* WkT = (u16*)alloc((size_t)512*512*2);
  u16* WqT = (u16*)alloc((size_t)512*512*2);
  u16* WvT = (u16*)alloc((size_t)512*512*2);
  u16* WoT = (u16*)alloc((size_t)512*512*2);
  u16* qws = (u16*)alloc((size_t)8*8*1024*64*2);   // [B,H,L,64], pre-scaled 1/8
  u16* kws = (u16*)alloc((size_t)8*8*1024*64*2);   // [B,H,L,64]
  u16* vt  = (u16*)alloc((size_t)8*8*1024*64*2);   // [B,H,64,L]
  // 32MB region: first xq/xk/xv (bf16 inputs), later overwritten by packed —
  // safe: stream is serial; QKV gemms consume x* before k_pack writes.
  char* shared32 = (char*)alloc((size_t)8*1024*1024*4);
  u16* xq = (u16*)shared32;
  u16* xk = (u16*)(shared32 + (size_t)8192*512*2);
  u16* xv = (u16*)(shared32 + (size_t)2*8192*512*2);
  u32* packed = (u32*)shared32;
  u16* ctxb = (u16*)alloc((size_t)8192*512*2);     // [B,L,512] bf16
  u16* relk80 = (u16*)alloc((size_t)80*64*2);
  u16* relvT  = (u16*)alloc((size_t)64*96*2);
  if (off > ws_size) return;

  k_wt4<<<dim3(16,16,4), 256, 0, stream>>>(Wk, Wq, Wv, Wo, WkT, WqT, WvT, WoT);
  k_prep_rel<<<44, 256, 0, stream>>>(rek, rev, relk80, relvT);
  k_cvt3<<<dim3(4096,3), 256, 0, stream>>>(query, key, value, xq, xk, xv);

  GArg aq { xq, WqT, bq, (void*)qws, 1, 0.125f };
  GArg ak { xk, WkT, bk, (void*)kws, 1, 1.0f };
  GArg av { xv, WvT, bv, (void*)vt,  2, 1.0f };
  k_gemm<<<dim3(8,64,3), 256, 0, stream>>>(aq, ak, av);

  k_pack<<<8192, 256, 0, stream>>>(relm, relw, maskp, packed);

  k_attn<<<512, 256, 0, stream>>>(qws, kws, vt, relk80, relvT, te, packed, ctxb);

  GArg ao { ctxb, WoT, bo, d_out, 0, 1.0f };
  k_gemm<<<dim3(8,64,1), 256, 0, stream>>>(ao, ao, ao);
}

// Round 6
// 375.542 us; speedup vs baseline: 1.1170x; 1.0265x over previous
//
#include <hip/hip_runtime.h>
#include <stdint.h>

using f32x4  = __attribute__((ext_vector_type(4))) float;
using short8 = __attribute__((ext_vector_type(8))) short;
typedef unsigned short u16;
typedef unsigned int   u32;

// B=8, H=8, L=1024, DM=512, DK=DV=64.  M = B*L = 8192.

static __device__ __forceinline__ u16 f2bf(float f) {
  union { float f; u32 u; } v; v.f = f;
  u32 r = v.u + 0x7fffu + ((v.u >> 16) & 1u);   // RNE
  return (u16)(r >> 16);
}
static __device__ __forceinline__ float bf2f(u16 u) {
  union { u32 u; float f; } v; v.u = ((u32)u) << 16;
  return v.f;
}

// async global->LDS, 16B per lane; LDS dest = wave-uniform base + lane*16
#define GLDS16(g, l) __builtin_amdgcn_global_load_lds( \
    (const __attribute__((address_space(1))) u32*)(g), \
    (__attribute__((address_space(3))) u32*)(l), 16, 0, 0)

// ------- 4 weight transposes in one launch: W [512k][512n] -> Wt [n][k] bf16
__global__ __launch_bounds__(256) void k_wt4(const float* __restrict__ W0, const float* __restrict__ W1,
                                             const float* __restrict__ W2, const float* __restrict__ W3,
                                             u16* __restrict__ T0, u16* __restrict__ T1,
                                             u16* __restrict__ T2, u16* __restrict__ T3) {
  const float* W = (blockIdx.z == 0) ? W0 : (blockIdx.z == 1) ? W1 : (blockIdx.z == 2) ? W2 : W3;
  u16* T = (blockIdx.z == 0) ? T0 : (blockIdx.z == 1) ? T1 : (blockIdx.z == 2) ? T2 : T3;
  __shared__ float t[32][33];
  int tx = threadIdx.x & 31, ty = threadIdx.x >> 5;   // 32 x 8
  int x0 = blockIdx.x * 32, y0 = blockIdx.y * 32;     // x = n, y = k
  #pragma unroll
  for (int i = 0; i < 4; i++)
    t[ty + i*8][tx] = W[(y0 + ty + i*8) * 512 + (x0 + tx)];
  __syncthreads();
  #pragma unroll
  for (int i = 0; i < 4; i++)
    T[(x0 + ty + i*8) * 512 + (y0 + tx)] = f2bf(t[tx][ty + i*8]);
}

// ------------- rel embeddings: relk80 [80][64] (zero-pad rows>=65),
//               relvT [64 dv][96 bucket] (zero-pad buckets>=65) -------------
__global__ __launch_bounds__(256) void k_prep_rel(const float* __restrict__ rk,
                                                  const float* __restrict__ rv,
                                                  u16* __restrict__ relk80,
                                                  u16* __restrict__ relvT) {
  int i = blockIdx.x * 256 + threadIdx.x;
  if (i < 80*64) {
    int row = i >> 6;
    relk80[i] = (row < 65) ? f2bf(rk[i]) : (u16)0;
  }
  int j = i - 80*64;
  if (j >= 0 && j < 64*96) {
    int dv = j / 96, bk = j % 96;
    relvT[j] = (bk < 65) ? f2bf(rv[bk*64 + dv]) : (u16)0;
  }
}

// ------------- fp32 -> bf16 for query/key/value in one launch -------------
__global__ __launch_bounds__(256) void k_cvt3(const float* __restrict__ a, const float* __restrict__ b,
                                              const float* __restrict__ c,
                                              u16* __restrict__ oa, u16* __restrict__ ob,
                                              u16* __restrict__ oc) {
  const float* src = (blockIdx.y == 0) ? a : (blockIdx.y == 1) ? b : c;
  u16* dst = (blockIdx.y == 0) ? oa : (blockIdx.y == 1) ? ob : oc;
  int i = blockIdx.x * 256 + threadIdx.x;
  float4 v = ((const float4*)src)[i];
  ushort4 o;
  o.x = f2bf(v.x); o.y = f2bf(v.y); o.z = f2bf(v.z); o.w = f2bf(v.w);
  ((ushort4*)dst)[i] = o;
}

// ------------- pack rel_matrix | mask<<7 | bf16(rel_mask)<<16 -> u32 -------
__global__ __launch_bounds__(256) void k_pack(const int* __restrict__ rm,
                                              const float* __restrict__ rw,
                                              const unsigned char* __restrict__ mk,
                                              u32* __restrict__ outp) {
  int i = blockIdx.x * 256 + threadIdx.x;     // x4 elements
  int4   r4 = ((const int4*)rm)[i];
  float4 w4 = ((const float4*)rw)[i];
  uchar4 m4 = ((const uchar4*)mk)[i];
  uint4 o;
  o.x = (u32)(r4.x & 63) | (m4.x ? 128u : 0u) | ((u32)f2bf(w4.x) << 16);
  o.y = (u32)(r4.y & 63) | (m4.y ? 128u : 0u) | ((u32)f2bf(w4.y) << 16);
  o.z = (u32)(r4.z & 63) | (m4.z ? 128u : 0u) | ((u32)f2bf(w4.z) << 16);
  o.w = (u32)(r4.w & 63) | (m4.w ? 128u : 0u) | ((u32)f2bf(w4.w) << 16);
  ((uint4*)outp)[i] = o;
}

// ---------------- bf16 MFMA GEMM: C = A[8192,512] @ Wt^T + bias -----------
// A bf16 row-major, Wt [n][k] bf16.  Tile M=128, N=64, BK=32; grid (8,64,z).
// Staging via global_load_lds width=16.  Epilogue: acc -> LDS tile -> WIDE
// contiguous stores (the R1-R5 invariant ~245us was the 2B-scatter stores of
// modes 1/2: one cache line per 2B store, ~25M L2 write transactions).
// mode 0: fp32 out [m][n] direct;  mode 1: bf16 [b,h,l,d];  mode 2: bf16 [b,h,d,l].
struct GArg { const u16* A; const u16* Wt; const float* bias; void* out; int mode; float scale; };

__global__ __launch_bounds__(256) void k_gemm(GArg g0, GArg g1, GArg g2) {
  GArg ar = (blockIdx.z == 0) ? g0 : (blockIdx.z == 1) ? g1 : g2;
  __shared__ u16 As[128*32];   // chunk c (16B) at byte c*16: row=c>>2, slot=c&3
  __shared__ u16 Bs[64*32];
  __shared__ u16 Cs[9216];     // mode1: [128][72] pad; mode2 (transposed): [64][136] pad
  int tid = threadIdx.x, lane = tid & 63, wv = tid >> 6;
  int quad = lane >> 4, l15 = lane & 15;
  int n0 = blockIdx.x * 64, m0 = blockIdx.y * 128;
  int wm = (wv >> 1) * 64, wn = (wv & 1) * 32;
  f32x4 acc[4][2];
  #pragma unroll
  for (int i = 0; i < 4; i++)
    #pragma unroll
    for (int j = 0; j < 2; j++)
      acc[i][j] = (f32x4){0.f, 0.f, 0.f, 0.f};

  const u16* Abase = ar.A  + (size_t)m0 * 512;
  const u16* Bbase = ar.Wt + (size_t)n0 * 512;
  int cA0 = wv * 128, cB0 = wv * 64;      // wave-uniform chunk bases

  for (int k0 = 0; k0 < 512; k0 += 32) {
    #pragma unroll
    for (int i = 0; i < 2; i++) {
      int c = cA0 + i*64 + lane;
      GLDS16(Abase + (c >> 2)*512 + k0 + (c & 3)*8, &As[(cA0 + i*64)*8]);
    }
    {
      int c = cB0 + lane;
      GLDS16(Bbase + (c >> 2)*512 + k0 + (c & 3)*8, &Bs[cB0*8]);
    }
    __syncthreads();
    short8 af[4], bf[2];
    #pragma unroll
    for (int i = 0; i < 4; i++) af[i] = *(const short8*)&As[(wm + i*16 + l15)*32 + quad*8];
    #pragma unroll
    for (int j = 0; j < 2; j++) bf[j] = *(const short8*)&Bs[(wn + j*16 + l15)*32 + quad*8];
    #pragma unroll
    for (int i = 0; i < 4; i++)
      #pragma unroll
      for (int j = 0; j < 2; j++)
        acc[i][j] = __builtin_amdgcn_mfma_f32_16x16x32_bf16(af[i], bf[j], acc[i][j], 0, 0, 0);
    __syncthreads();
  }

  if (ar.mode == 0) {
    #pragma unroll
    for (int i = 0; i < 4; i++)
      #pragma unroll
      for (int j = 0; j < 2; j++) {
        int ncol = n0 + wn + j*16 + l15;
        float bv = ar.bias[ncol];
        #pragma unroll
        for (int r = 0; r < 4; r++) {
          int m = m0 + wm + i*16 + quad*4 + r;
          ((float*)ar.out)[m*512 + ncol] = (acc[i][j][r] + bv) * ar.scale;
        }
      }
  } else {
    // acc -> LDS tile (bias+scale applied)
    #pragma unroll
    for (int i = 0; i < 4; i++)
      #pragma unroll
      for (int j = 0; j < 2; j++) {
        int nloc = wn + j*16 + l15;
        float bv = ar.bias[n0 + nloc];
        #pragma unroll
        for (int r = 0; r < 4; r++) {
          int mloc = wm + i*16 + quad*4 + r;
          float val = (acc[i][j][r] + bv) * ar.scale;
          if (ar.mode == 1) Cs[mloc*72 + nloc] = f2bf(val);
          else              Cs[nloc*136 + mloc] = f2bf(val);
        }
      }
    __syncthreads();
    int bb = m0 >> 10, hh = n0 >> 6, mbase = m0 & 1023;
    u16* outp = (u16*)ar.out;
    if (ar.mode == 1) {
      // [b,h,l,d]: 128 rows x 128B contiguous
      size_t base = ((size_t)(bb*8 + hh)*1024 + mbase)*64;
      #pragma unroll
      for (int p = 0; p < 4; p++) {
        int mloc = (tid >> 3) + p*32, seg = tid & 7;
        *(short8*)(outp + base + (size_t)mloc*64 + seg*8) = *(const short8*)&Cs[mloc*72 + seg*8];
      }
    } else {
      // [b,h,d,l]: 64 rows x 256B contiguous
      size_t base = (size_t)(bb*8 + hh)*64*1024 + mbase;
      #pragma unroll
      for (int p = 0; p < 4; p++) {
        int d = (tid >> 4) + p*16, seg = tid & 15;
        *(short8*)(outp + base + (size_t)d*1024 + seg*8) = *(const short8*)&Cs[d*136 + seg*8];
      }
    }
  }
}

// ---------------- fused attention (UNCHANGED from R5) ----------------
__global__ __launch_bounds__(256, 2) void k_attn(
    const u16* __restrict__ qws, const u16* __restrict__ kws, const u16* __restrict__ vtws,
    const u16* __restrict__ relk80, const u16* __restrict__ relvT,
    const float* __restrict__ tree_emb, const u32* __restrict__ packed,
    u16* __restrict__ ctx) {
  __shared__ u16 qdotL[8*16*68];    // [h][q][bucket]  (band phase only)
  __shared__ u16 PB[8][16*96];      // per-head banded P
  __shared__ u16 Pl[4][2][16*40];   // per-wave C->A bridge, stride 40
  __shared__ u32 treecP[256];       // [vocab][w]: lo=head w, hi=head w+4 (bf16)

  int tid = threadIdx.x, lane = tid & 63, wv = tid >> 6;
  int quad = lane >> 4, l15 = lane & 15;
  int b = blockIdx.x & 7, qt = blockIdx.x >> 3;
  int q0 = qt * 16;

  if (tid < 256) {
    int v = tid >> 2, w2 = tid & 3;
    treecP[v*4 + w2] = (u32)f2bf(tree_emb[v*8 + w2]) | ((u32)f2bf(tree_emb[v*8 + w2 + 4]) << 16);
  }
  for (int i = tid; i < 8*16*96/2; i += 256) ((u32*)PB)[i] = 0u;

  const u16* qb[2] = { qws + (size_t)(b*8 + wv)*(1024*64),
                       qws + (size_t)(b*8 + wv + 4)*(1024*64) };
  const u16* kb[2] = { kws + (size_t)(b*8 + wv)*(1024*64),
                       kws + (size_t)(b*8 + wv + 4)*(1024*64) };
  const u16* vb[2] = { vtws + (size_t)(b*8 + wv)*(64*1024),
                       vtws + (size_t)(b*8 + wv + 4)*(64*1024) };
  const u32* pkb = packed + ((size_t)b << 20);

  short8 aQ[2][2];
  #pragma unroll
  for (int h2 = 0; h2 < 2; h2++)
    #pragma unroll
    for (int kf = 0; kf < 2; kf++)
      aQ[h2][kf] = *(const short8*)(qb[h2] + (q0 + l15)*64 + kf*32 + quad*8);

  float qd0[2][4], qd64[2][4];
  #pragma unroll
  for (int h2 = 0; h2 < 2; h2++) {
    #pragma unroll
    for (int t = 0; t < 5; t++) {
      f32x4 C = (f32x4){0.f,0.f,0.f,0.f};
      #pragma unroll
      for (int kf = 0; kf < 2; kf++) {
        short8 bR = *(const short8*)(relk80 + (t*16 + l15)*64 + kf*32 + quad*8);
        C = __builtin_amdgcn_mfma_f32_16x16x32_bf16(aQ[h2][kf], bR, C, 0, 0, 0);
      }
      if (t == 0) {
        #pragma unroll
        for (int r = 0; r < 4; r++) qd0[h2][r] = __shfl(C[r], lane & 48, 64);
      }
      if (t == 4) {
        #pragma unroll
        for (int r = 0; r < 4; r++) qd64[h2][r] = __shfl(C[r], lane & 48, 64);
      }
      int col = t*16 + l15;
      if (col < 65) {
        #pragma unroll
        for (int r = 0; r < 4; r++)
          qdotL[((wv + h2*4)*16 + quad*4 + r)*68 + col] = f2bf(C[r]);
      }
    }
  }
  __syncthreads();

  int t_lo = max(0, (q0 - 31) >> 5);
  int t_hi = min(31, (q0 + 46) >> 5);

  short8 kreg[2][2][2];
  #pragma unroll
  for (int h2 = 0; h2 < 2; h2++)
    #pragma unroll
    for (int ct = 0; ct < 2; ct++)
      #pragma unroll
      for (int kf = 0; kf < 2; kf++)
        kreg[h2][ct][kf] = *(const short8*)(kb[h2] + (ct*16 + l15)*64 + kf*32 + quad*8);
  u32 pk[8];
  #pragma unroll
  for (int e = 0; e < 8; e++) {
    int ct = e >> 2, r = e & 3;
    pk[e] = pkb[((q0 + quad*4 + r) << 10) + ct*16 + l15];
  }

  f32x4 O[2][4];
  float rs[2][4], ts0[2][4], ts1[2][4];
  #pragma unroll
  for (int h2 = 0; h2 < 2; h2++) {
    #pragma unroll
    for (int t = 0; t < 4; t++) O[h2][t] = (f32x4){0.f,0.f,0.f,0.f};
    #pragma unroll
    for (int r = 0; r < 4; r++) { rs[h2][r] = 0.f; ts0[h2][r] = 0.f; ts1[h2][r] = 0.f; }
  }

  for (int it = 0; it < 32; ++it) {
    int k0 = it << 5;
    int kn = (it + 1 < 32) ? (k0 + 32) : 0;
    short8 vreg[2][4];
    #pragma unroll
    for (int h2 = 0; h2 < 2; h2++)
      #pragma unroll
      for (int t = 0; t < 4; t++)
        vreg[h2][t] = *(const short8*)(vb[h2] + (t*16 + l15)*1024 + k0 + quad*8);

    f32x4 S[2][2];
    #pragma unroll
    for (int h2 = 0; h2 < 2; h2++)
      #pragma unroll
      for (int ct = 0; ct < 2; ct++) {
        f32x4 c = (f32x4){0.f,0.f,0.f,0.f};
        #pragma unroll
        for (int kf = 0; kf < 2; kf++)
          c = __builtin_amdgcn_mfma_f32_16x16x32_bf16(aQ[h2][kf], kreg[h2][ct][kf], c, 0, 0, 0);
        S[h2][ct] = c;
      }
    #pragma unroll
    for (int h2 = 0; h2 < 2; h2++)
      #pragma unroll
      for (int ct = 0; ct < 2; ct++)
        #pragma unroll
        for (int kf = 0; kf < 2; kf++)
          kreg[h2][ct][kf] = *(const short8*)(kb[h2] + (kn + ct*16 + l15)*64 + kf*32 + quad*8);
    u32 pkc[8];
    #pragma unroll
    for (int e = 0; e < 8; e++) pkc[e] = pk[e];
    #pragma unroll
    for (int e = 0; e < 8; e++) {
      int ct = e >> 2, r = e & 3;
      pk[e] = pkb[((q0 + quad*4 + r) << 10) + kn + ct*16 + l15];
    }

    if (it < t_lo || it > t_hi) {
      bool pre = it < t_lo;
      #pragma unroll
      for (int ct = 0; ct < 2; ct++) {
        #pragma unroll
        for (int r = 0; r < 4; r++) {
          u32 sg = pkc[ct*4 + r];
          float rw = bf2f((u16)(sg >> 16));
          float mb = (sg & 128u) ? -1e30f : 0.f;
          u32 tp = treecP[(sg & 63u)*4 + wv];
          #pragma unroll
          for (int h2 = 0; h2 < 2; h2++) {
            float tb = bf2f((u16)(h2 ? (tp >> 16) : (tp & 0xffffu)));
            float qv = pre ? qd0[h2][r] : qd64[h2][r];
            float p = __expf(S[h2][ct][r] + qv + tb*rw + mb);
            rs[h2][r]  += p;
            ts0[h2][r] += pre ? p : 0.f;
            ts1[h2][r] += pre ? 0.f : p;
            Pl[wv][h2][(quad*4 + r)*40 + ct*16 + l15] = f2bf(p);
          }
        }
      }
    } else {
      #pragma unroll
      for (int ct = 0; ct < 2; ct++) {
        #pragma unroll
        for (int r = 0; r < 4; r++) {
          int kloc = ct*16 + l15, qloc = quad*4 + r;
          int d = (k0 + kloc) - (q0 + qloc);
          int bucket = min(max(d + 32, 0), 64);
          u32 sg = pkc[ct*4 + r];
          float rw = bf2f((u16)(sg >> 16));
          float mb = (sg & 128u) ? -1e30f : 0.f;
          u32 tp = treecP[(sg & 63u)*4 + wv];
          #pragma unroll
          for (int h2 = 0; h2 < 2; h2++) {
            float qd = bf2f(qdotL[((wv + h2*4)*16 + qloc)*68 + bucket]);
            float tb = bf2f((u16)(h2 ? (tp >> 16) : (tp & 0xffffu)));
            float p = __expf(S[h2][ct][r] + qd + tb*rw + mb);
            rs[h2][r] += p;
            if (d <= -32)      ts0[h2][r] += p;
            else if (d >= 32)  ts1[h2][r] += p;
            else               PB[wv + h2*4][qloc*96 + d + 32] = f2bf(p);
            Pl[wv][h2][qloc*40 + kloc] = f2bf(p);
          }
        }
      }
    }

    #pragma unroll
    for (int h2 = 0; h2 < 2; h2++) {
      short8 aP = *(const short8*)&Pl[wv][h2][l15*40 + quad*8];
      #pragma unroll
      for (int t = 0; t < 4; t++)
        O[h2][t] = __builtin_amdgcn_mfma_f32_16x16x32_bf16(aP, vreg[h2][t], O[h2][t], 0, 0, 0);
    }
  }

  #pragma unroll
  for (int m = 1; m < 16; m <<= 1) {
    #pragma unroll
    for (int h2 = 0; h2 < 2; h2++)
      #pragma unroll
      for (int r = 0; r < 4; r++) {
        rs[h2][r]  += __shfl_xor(rs[h2][r],  m, 64);
        ts0[h2][r] += __shfl_xor(ts0[h2][r], m, 64);
        ts1[h2][r] += __shfl_xor(ts1[h2][r], m, 64);
      }
  }
  if (l15 == 0) {
    #pragma unroll
    for (int h2 = 0; h2 < 2; h2++)
      #pragma unroll
      for (int r = 0; r < 4; r++) {
        PB[wv + h2*4][(quad*4 + r)*96 + 0]  = f2bf(ts0[h2][r]);
        PB[wv + h2*4][(quad*4 + r)*96 + 64] = f2bf(ts1[h2][r]);
      }
  }
  __syncthreads();

  #pragma unroll
  for (int h2 = 0; h2 < 2; h2++) {
    short8 aB[3];
    #pragma unroll
    for (int s = 0; s < 3; s++)
      aB[s] = *(const short8*)&PB[wv + h2*4][l15*96 + s*32 + quad*8];
    #pragma unroll
    for (int t = 0; t < 4; t++)
      #pragma unroll
      for (int s = 0; s < 3; s++) {
        short8 bRV = *(const short8*)(relvT + (t*16 + l15)*96 + s*32 + quad*8);
        O[h2][t] = __builtin_amdgcn_mfma_f32_16x16x32_bf16(aB[s], bRV, O[h2][t], 0, 0, 0);
      }
  }

  #pragma unroll
  for (int h2 = 0; h2 < 2; h2++) {
    float inv[4];
    #pragma unroll
    for (int r = 0; r < 4; r++) inv[r] = 1.0f / rs[h2][r];
    #pragma unroll
    for (int t = 0; t < 4; t++)
      #pragma unroll
      for (int r = 0; r < 4; r++) {
        int qg = q0 + quad*4 + r;
        ctx[(b*1024 + qg)*512 + (wv + h2*4)*64 + t*16 + l15] = f2bf(O[h2][t][r] * inv[r]);
      }
  }
}

extern "C" void kernel_launch(void* const* d_in, const int* in_sizes, int n_in,
                              void* d_out, int out_size, void* d_ws, size_t ws_size,
                              hipStream_t stream) {
  const float* key   = (const float*)d_in[0];
  const float* value = (const float*)d_in[1];
  const float* query = (const float*)d_in[2];
  const unsigned char* maskp = (const unsigned char*)d_in[3];
  const int*   relm  = (const int*)d_in[4];
  const float* relw  = (const float*)d_in[5];
  const float* Wk = (const float*)d_in[6];
  const float* bk = (const float*)d_in[7];
  const float* Wq = (const float*)d_in[8];
  const float* bq = (const float*)d_in[9];
  const float* Wv = (const float*)d_in[10];
  const float* bv = (const float*)d_in[11];
  const float* Wo = (const float*)d_in[12];
  const float* bo = (const float*)d_in[13];
  const float* rek = (const float*)d_in[14];
  const float* rev = (const float*)d_in[15];
  const float* te  = (const float*)d_in[16];
  (void)in_sizes; (void)n_in; (void)out_size;

  char* w = (char*)d_ws;
  size_t off = 0;
  auto alloc = [&](size_t bytes) -> void* {
    void* p = w + off; off += (bytes + 255) & ~(size_t)255; return p;
  };
  u16* WkT = (u16*)alloc((size_t)512*512*2);
  u16* WqT = (u16*)alloc((size_t)512*512*2);
  u16* WvT = (u16*)alloc((size_t)512*512*2);
  u16* WoT = (u16*)alloc((size_t)512*512*2);
  u16* qws = (u16*)alloc((size_t)8*8*1024*64*2);   // [B,H,L,64], pre-scaled 1/8
  u16* kws = (u16*)alloc((size_t)8*8*1024*64*2);   // [B,H,L,64]
  u16* vt  = (u16*)alloc((size_t)8*8*1024*64*2);   // [B,H,64,L]
  // 32MB region: first xq/xk/xv (bf16 inputs), later overwritten by packed —
  // safe: stream is serial; QKV gemms consume x* before k_pack writes.
  char* shared32 = (char*)alloc((size_t)8*1024*1024*4);
  u16* xq = (u16*)shared32;
  u16* xk = (u16*)(shared32 + (size_t)8192*512*2);
  u16* xv = (u16*)(shared32 + (size_t)2*8192*512*2);
  u32* packed = (u32*)shared32;
  u16* ctxb = (u16*)alloc((size_t)8192*512*2);     // [B,L,512] bf16
  u16* relk80 = (u16*)alloc((size_t)80*64*2);
  u16* relvT  = (u16*)alloc((size_t)64*96*2);
  if (off > ws_size) return;

  k_wt4<<<dim3(16,16,4), 256, 0, stream>>>(Wk, Wq, Wv, Wo, WkT, WqT, WvT, WoT);
  k_prep_rel<<<44, 256, 0, stream>>>(rek, rev, relk80, relvT);
  k_cvt3<<<dim3(4096,3), 256, 0, stream>>>(query, key, value, xq, xk, xv);

  GArg aq { xq, WqT, bq, (void*)qws, 1, 0.125f };
  GArg ak { xk, WkT, bk, (void*)kws, 1, 1.0f };
  GArg av { xv, WvT, bv, (void*)vt,  2, 1.0f };
  k_gemm<<<dim3(8,64,3), 256, 0, stream>>>(aq, ak, av);

  k_pack<<<8192, 256, 0, stream>>>(relm, relw, maskp, packed);

  k_attn<<<512, 256, 0, stream>>>(qws, kws, vt, relk80, relvT, te, packed, ctxb);

  GArg ao { ctxb, WoT, bo, d_out, 0, 1.0f };
  k_gemm<<<dim3(8,64,1), 256, 0, stream>>>(ao, ao, ao);
}